// Round 8
// baseline (352.250 us; speedup 1.0000x reference)
//
#include <hip/hip_runtime.h>
#include <hip/hip_fp16.h>

#define HH 8
#define NL 4
#define NP 4
#define DDIM 256
#define HD 32
#define BSZ 4
#define NQQ 22500
#define NVV 29930

typedef __attribute__((ext_vector_type(4))) float f32x4;
typedef __attribute__((ext_vector_type(8))) short s16x8;
typedef __attribute__((ext_vector_type(4))) unsigned int u32x4;
typedef __attribute__((ext_vector_type(2))) __fp16 f16x2;

__device__ __forceinline__ s16x8 cvt8(f32x4 a, f32x4 b) {  // 8 f32 -> 8 f16 (RTZ, packed)
    union { f16x2 h[4]; s16x8 v; } r;
    r.h[0] = __builtin_amdgcn_cvt_pkrtz(a[0], a[1]);
    r.h[1] = __builtin_amdgcn_cvt_pkrtz(a[2], a[3]);
    r.h[2] = __builtin_amdgcn_cvt_pkrtz(b[0], b[1]);
    r.h[3] = __builtin_amdgcn_cvt_pkrtz(b[2], b[3]);
    return r.v;
}
__device__ __forceinline__ unsigned int wpair(float w) {   // (w,w) as packed f16x2
    union { f16x2 h; unsigned int u; } x;
    x.h = __builtin_amdgcn_cvt_pkrtz(w, w);
    return x.u;
}
__device__ __forceinline__ void pkfma16(unsigned int& acc, unsigned int v, unsigned int w) {
    asm("v_pk_fma_f16 %0, %1, %2, %0" : "+v"(acc) : "v"(v), "v"(w));
}

// ---------------------------------------------------------------------------
// k_pack: weights -> f16 MFMA B-fragment order (RNE).
//   elem i of lane l <-> k = ks*32 + (l>>4)*8 + i, col = l&15
// ---------------------------------------------------------------------------
__global__ __launch_bounds__(64) void k_pack(
    const float* __restrict__ Wso, const float* __restrict__ Waw,
    const float* __restrict__ Wv,  const float* __restrict__ Wo,
    unsigned short* __restrict__ pWv, unsigned short* __restrict__ pQP,
    unsigned short* __restrict__ pWo)
{
    const int ctg = blockIdx.x;      // 0..15 Wv, 16..39 qproj(Wso|Waw), 40..55 Wo
    const int lane = threadIdx.x;
    const float* src; unsigned short* dst; int N, col, ct;
    if (ctg < 16)      { ct = ctg;      dst = pWv; src = Wv; N = 256; col = ct*16 + (lane&15); }
    else if (ctg < 40) { ct = ctg - 16; dst = pQP;
        if (ct < 16) { src = Wso; N = 256; col = ct*16 + (lane&15); }
        else         { src = Waw; N = 128; col = (ct-16)*16 + (lane&15); } }
    else               { ct = ctg - 40; dst = pWo; src = Wo; N = 256; col = ct*16 + (lane&15); }

    for (int ks = 0; ks < 8; ++ks) {
        const int k0 = ks*32 + (lane>>4)*8;
        unsigned short tmp[8];
#pragma unroll
        for (int i = 0; i < 8; ++i)
            tmp[i] = __half_as_ushort(__float2half(src[(size_t)(k0 + i) * N + col]));
        unsigned short* d = dst + ((size_t)(ct*8 + ks)*64 + lane)*8;
#pragma unroll
        for (int i = 0; i < 8; ++i) d[i] = tmp[i];
    }
}

// ---------------------------------------------------------------------------
// k_value_proj: v = value @ W_v + b_v -> f16 (b,h,n,d). MFMA, no LDS.
// ---------------------------------------------------------------------------
__global__ __launch_bounds__(256) void k_value_proj(
    const float* __restrict__ value,        // [BSZ][NVV][256]
    const float* __restrict__ bv,           // [256]
    const unsigned short* __restrict__ pWv, // packed B-frags (f16)
    unsigned short* __restrict__ vout)      // [BSZ][HH][NVV][HD] f16 bits
{
    const int tid = threadIdx.x;
    const int b   = blockIdx.y;
    const int row0 = blockIdx.x * 64;
    const int w = tid >> 6, lane = tid & 63;
    const int mrow = lane & 15, kg = lane >> 4;

    const int rowa = row0 + w*16 + mrow;
    const bool rv = rowa < NVV;
    const float* ap = value + ((size_t)b * NVV + (rv ? rowa : 0)) * DDIM + kg*8;

    s16x8 af[8];
#pragma unroll
    for (int ks = 0; ks < 8; ++ks) {
        f32x4 a0 = {0.f,0.f,0.f,0.f}, a1 = a0;
        if (rv) {
            a0 = __builtin_nontemporal_load((const f32x4*)(ap + ks*32));
            a1 = __builtin_nontemporal_load((const f32x4*)(ap + ks*32 + 4));
        }
        af[ks] = cvt8(a0, a1);
    }
    const s16x8* bp = (const s16x8*)pWv;
#pragma unroll 2
    for (int ct = 0; ct < 16; ++ct) {
        const float bias = bv[ct*16 + mrow];
        f32x4 acc = {bias, bias, bias, bias};
#pragma unroll
        for (int ks = 0; ks < 8; ++ks)
            acc = __builtin_amdgcn_mfma_f32_16x16x32_f16(af[ks], bp[(ct*8 + ks)*64 + lane], acc, 0, 0, 0);
        const int h = ct >> 1, d = (ct & 1)*16 + mrow;
        unsigned short* vp = vout + ((size_t)(b*HH + h) * NVV) * HD + d;
#pragma unroll
        for (int r = 0; r < 4; ++r) {
            const int rowd = row0 + w*16 + kg*4 + r;
            if (rowd < NVV) vp[(size_t)rowd * HD] = __half_as_ushort(__float2half(acc[r]));  // RNE
        }
    }
}

// ---------------------------------------------------------------------------
// k_query_fused: QB=16, 256 thr, 25.6 KB LDS -> 6 blocks/CU (24 waves).
// s_so is f16 [h][idx*17 + q]; s_aw f32 [h][lp*17 + q].
// ---------------------------------------------------------------------------
__global__ __launch_bounds__(256, 6) void k_query_fused(
    const float* __restrict__ query,   // [BSZ][NQQ][256]
    const float* __restrict__ refpt,   // [BSZ][NQQ][NL][2]
    const unsigned short* __restrict__ pQP, // packed Wso|Waw frags (24 cts)
    const unsigned short* __restrict__ pWo, // packed Wo frags (16 cts)
    const float* __restrict__ bso, const float* __restrict__ baw,
    const float* __restrict__ bo,
    const unsigned short* __restrict__ v,   // [BSZ][HH][NVV][HD] f16 bits
    float* __restrict__ out)           // [BSZ][NQQ][256]
{
    __shared__ __align__(16) unsigned char s_a8[16 * 512];  // f16 [16][256] swizzled (8 KB)
    __shared__ unsigned short s_so[8 * 544]; // [h][(lp*2+xy)*17 + q] f16  (8.7 KB)
    __shared__ float s_aw[8 * 272];          // [h][lp*17 + q]            (8.7 KB)

    const int tid = threadIdx.x;
    const int b   = blockIdx.y;
    const int q0  = blockIdx.x * 16;
    const int w = tid >> 6, lane = tid & 63;
    const int mrow = lane & 15, kg = lane >> 4;

    // ---- stage q tile -> f16 swizzled LDS ----
    {
        const int r  = tid >> 4;         // 0..15
        const int c0 = (tid & 15) * 16;  // 16 cols per thread
        const bool rv = (q0 + r) < NQQ;
        const float* qrow = query + ((size_t)b * NQQ + q0 + r) * DDIM + c0;
        f32x4 a0 = {0,0,0,0}, a1 = a0, a2 = a0, a3 = a0;
        if (rv) {
            a0 = __builtin_nontemporal_load((const f32x4*)(qrow));
            a1 = __builtin_nontemporal_load((const f32x4*)(qrow+4));
            a2 = __builtin_nontemporal_load((const f32x4*)(qrow+8));
            a3 = __builtin_nontemporal_load((const f32x4*)(qrow+12));
        }
        const int base = r*512 + c0*2;
        const int sw = (r & 7) << 4;
        *(s16x8*)(s_a8 + ((base     ) ^ sw)) = cvt8(a0, a1);
        *(s16x8*)(s_a8 + ((base + 16) ^ sw)) = cvt8(a2, a3);
    }
    __syncthreads();

    // ---- phases A+B: [so | aw] = q @ [Wso | Waw] + bias, MFMA f16 ----
    {
        s16x8 af[8];
        const int swz = (mrow & 7) << 4;
#pragma unroll
        for (int ks = 0; ks < 8; ++ks)
            af[ks] = *(const s16x8*)(s_a8 + ((mrow*512 + (ks*32 + kg*8)*2) ^ swz));
        const s16x8* bq = (const s16x8*)pQP;
#pragma unroll
        for (int t = 0; t < 6; ++t) {
            const int ct = w*6 + t;
            const float bias = (ct < 16) ? bso[ct*16 + mrow] : baw[(ct-16)*16 + mrow];
            f32x4 acc = {bias, bias, bias, bias};
#pragma unroll
            for (int ks = 0; ks < 8; ++ks)
                acc = __builtin_amdgcn_mfma_f32_16x16x32_f16(af[ks], bq[(ct*8 + ks)*64 + lane], acc, 0, 0, 0);
            if (ct < 16) {
                const int c = ct*16 + mrow;           // so col 0..255
                unsigned short* d = s_so + (c >> 5)*544 + (c & 31)*17 + kg*4;
#pragma unroll
                for (int r = 0; r < 4; ++r)
                    d[r] = __half_as_ushort(__float2half(acc[r]));  // RNE f16
            } else {
                const int c = (ct-16)*16 + mrow;      // aw col 0..127
                float* d = s_aw + (c >> 4)*272 + (c & 15)*17 + kg*4;
#pragma unroll
                for (int r = 0; r < 4; ++r) d[r] = acc[r];
            }
        }
    }
    __syncthreads();

    // ---- softmax over 16 (l,p) per (q,h); q=tid&15 keeps banks spread ----
    if (tid < 128) {
        const int q = tid & 15, h = tid >> 4;
        float* p = s_aw + h * 272 + q;   // elements at p[i*17]
        float m = p[0];
#pragma unroll
        for (int i = 1; i < 16; ++i) m = fmaxf(m, p[i*17]);
        float e[16], s = 0.f;
#pragma unroll
        for (int i = 0; i < 16; ++i) { e[i] = __expf(p[i*17] - m); s += e[i]; }
        const float inv = 1.f / s;
#pragma unroll
        for (int i = 0; i < 16; ++i) p[i*17] = e[i] * inv;
    }
    __syncthreads();
    // s_a8 q-tile dead from here; reused as res (f16, same swizzle).

    // ---- sampling: 4 lanes per (q,h); h wave-uniform; 16B (8-dim f16) gathers;
    //      packed v_pk_fma_f16 accumulation ----
    {
        const int qs = lane >> 2;        // 0..15
        const int dg = lane & 3;         // dims dg*8 .. dg*8+7
        const int qv = (q0 + qs < NQQ) ? (q0 + qs) : (NQQ - 1);
        const float2* rp2 = (const float2*)(refpt + ((size_t)b * NQQ + qv) * (NL * 2));
#pragma unroll
        for (int pass = 0; pass < 2; ++pass) {
            const int h = __builtin_amdgcn_readfirstlane(pass * 4 + w);
            const unsigned short* vbh = v + ((size_t)(b*HH + h) * NVV) * HD + dg*8;
            const unsigned short* soh = s_so + h * 544 + qs;
            const float* awh = s_aw + h * 272 + qs;
            unsigned int acc0 = 0, acc1 = 0, acc2 = 0, acc3 = 0;  // packed f16x2
            const int hs_[4] = {150, 75, 38, 19};
            const int st_[4] = {0, 22500, 28125, 29569};
#pragma unroll
            for (int l = 0; l < NL; ++l) {
                const int L = hs_[l];
                const float Lf = (float)L;
                const float2 rxy = rp2[l];
                const unsigned short* vlp = vbh + (size_t)st_[l] * HD;
#pragma unroll
                for (int p = 0; p < NP; ++p) {
                    const int lp = l*4 + p;
                    const float ox  = __half2float(__ushort_as_half(soh[(2*lp    ) * 17]));
                    const float oy  = __half2float(__ushort_as_half(soh[(2*lp + 1) * 17]));
                    const float awv = awh[lp * 17];
                    // norm == level size, so x = rx*L + ox - 0.5 exactly
                    const float x = fmaf(rxy.x, Lf, ox) - 0.5f;
                    const float y = fmaf(rxy.y, Lf, oy) - 0.5f;
                    const float xf = floorf(x), yf = floorf(y);
                    const float lx = x - xf, ly = y - yf;
                    const int x0 = (int)xf, y0 = (int)yf;
                    const int x1 = x0 + 1, y1 = y0 + 1;
                    const int cx0 = min(max(x0, 0), L-1), cx1 = min(max(x1, 0), L-1);
                    const int cy0 = min(max(y0, 0), L-1), cy1 = min(max(y1, 0), L-1);
                    const bool bx0 = (unsigned)x0 < (unsigned)L;
                    const bool bx1 = (unsigned)x1 < (unsigned)L;
                    const bool by0 = (unsigned)y0 < (unsigned)L;
                    const bool by1 = (unsigned)y1 < (unsigned)L;
                    const unsigned r0 = (unsigned)(cy0 * L), r1 = (unsigned)(cy1 * L);
                    const u32x4 c00 = *(const u32x4*)(vlp + (size_t)((r0 + cx0) * HD));
                    const u32x4 c10 = *(const u32x4*)(vlp + (size_t)((r0 + cx1) * HD));
                    const u32x4 c01 = *(const u32x4*)(vlp + (size_t)((r1 + cx0) * HD));
                    const u32x4 c11 = *(const u32x4*)(vlp + (size_t)((r1 + cx1) * HD));
                    const float t1 = awv * ly, t0 = awv - t1;
                    const float lxc = 1.f - lx;
                    const float w00 = (bx0 & by0) ? lxc * t0 : 0.f;
                    const float w10 = (bx1 & by0) ? lx  * t0 : 0.f;
                    const float w01 = (bx0 & by1) ? lxc * t1 : 0.f;
                    const float w11 = (bx1 & by1) ? lx  * t1 : 0.f;
#define CORNER(cv, wgt) { \
    const unsigned int wp_ = wpair(wgt); \
    pkfma16(acc0, (cv)[0], wp_); pkfma16(acc1, (cv)[1], wp_); \
    pkfma16(acc2, (cv)[2], wp_); pkfma16(acc3, (cv)[3], wp_); }
                    CORNER(c00, w00)
                    CORNER(c10, w10)
                    CORNER(c01, w01)
                    CORNER(c11, w11)
#undef CORNER
                }
            }
            u32x4 rb = {acc0, acc1, acc2, acc3};   // already packed f16 pairs
            const int boff = qs*512 + (h*32 + dg*8)*2;
            *(u32x4*)(s_a8 + (boff ^ ((qs & 7) << 4))) = rb;
        }
    }
    __syncthreads();

    // ---- phase O: out = res @ W_o + b_o, MFMA f16 ----
    {
        s16x8 of[8];
        const int swz = (mrow & 7) << 4;
#pragma unroll
        for (int ks = 0; ks < 8; ++ks)
            of[ks] = *(const s16x8*)(s_a8 + ((mrow*512 + (ks*32 + kg*8)*2) ^ swz));
        const s16x8* bp = (const s16x8*)pWo;
#pragma unroll
        for (int t = 0; t < 4; ++t) {
            const int ct = w*4 + t;
            const float bias = bo[ct*16 + mrow];
            f32x4 acc = {bias, bias, bias, bias};
#pragma unroll
            for (int ks = 0; ks < 8; ++ks)
                acc = __builtin_amdgcn_mfma_f32_16x16x32_f16(of[ks], bp[(ct*8 + ks)*64 + lane], acc, 0, 0, 0);
#pragma unroll
            for (int r = 0; r < 4; ++r) {
                const int q = kg*4 + r;
                if (q0 + q < NQQ)
                    __builtin_nontemporal_store(acc[r],
                        &out[((size_t)b * NQQ + q0 + q) * DDIM + ct*16 + mrow]);
            }
        }
    }
}

extern "C" void kernel_launch(void* const* d_in, const int* in_sizes, int n_in,
                              void* d_out, int out_size, void* d_ws, size_t ws_size,
                              hipStream_t stream) {
    const float* query = (const float*)d_in[0];
    const float* value = (const float*)d_in[1];
    const float* refpt = (const float*)d_in[2];
    const float* Wso = (const float*)d_in[5];
    const float* bso = (const float*)d_in[6];
    const float* Waw = (const float*)d_in[7];
    const float* baw = (const float*)d_in[8];
    const float* Wv  = (const float*)d_in[9];
    const float* bv  = (const float*)d_in[10];
    const float* Wo  = (const float*)d_in[11];
    const float* bo  = (const float*)d_in[12];
    float* out = (float*)d_out;

    // ws layout: v f16 (61,296,640 B) | pWv | pQP | pWo
    unsigned short* v   = (unsigned short*)d_ws;
    unsigned short* pWv = (unsigned short*)((char*)d_ws + 61296640);
    unsigned short* pQP = pWv + 65536;
    unsigned short* pWo = pQP + 98304;

    k_pack<<<56, 64, 0, stream>>>(Wso, Waw, Wv, Wo, pWv, pQP, pWo);

    dim3 g1((NVV + 63) / 64, BSZ);
    k_value_proj<<<g1, 256, 0, stream>>>(value, bv, pWv, v);

    dim3 g2((NQQ + 15) / 16, BSZ);
    k_query_fused<<<g2, 256, 0, stream>>>(query, refpt, pQP, pWo, bso, baw, bo, v, out);
}